// Round 2
// baseline (1356.467 us; speedup 1.0000x reference)
//
#include <hip/hip_runtime.h>
#include <hip/hip_bf16.h>

#define KS 5
#define K3 125
#define NHIST (K3 * 32)

__device__ inline float4 f4fma(float a, float4 b, float4 c) {
    c.x = fmaf(a, b.x, c.x); c.y = fmaf(a, b.y, c.y);
    c.z = fmaf(a, b.z, c.z); c.w = fmaf(a, b.w, c.w);
    return c;
}

// ---------------------------------------------------------------------------
// Spline basis per (edge, s): basis[e*8+s], widx[e*8+s]
// ---------------------------------------------------------------------------
__global__ void basis_kernel(const float* __restrict__ pseudo,
                             float* __restrict__ basis, int* __restrict__ widx,
                             int E) {
    int e = blockIdx.x * blockDim.x + threadIdx.x;
    if (e >= E) return;
    float fr[3];
    int bot[3];
#pragma unroll
    for (int d = 0; d < 3; ++d) {
        float v = pseudo[e * 3 + d] * (float)(KS - 1);
        float fl = fminf(floorf(v), (float)(KS - 2));
        fr[d] = v - fl;
        bot[d] = (int)fl;
    }
    const int strides[3] = {1, KS, KS * KS};
#pragma unroll
    for (int s = 0; s < 8; ++s) {
        float b = 1.f;
        int w = 0;
#pragma unroll
        for (int d = 0; d < 3; ++d) {
            int bit = (s >> d) & 1;
            b *= bit ? fr[d] : (1.f - fr[d]);
            w += (bot[d] + bit) * strides[d];
        }
        basis[e * 8 + s] = b;
        widx[e * 8 + s] = w;
    }
}

__global__ void deg_kernel(const int* __restrict__ dst, float* __restrict__ deg, int E) {
    int e = blockIdx.x * blockDim.x + threadIdx.x;
    if (e >= E) return;
    atomicAdd(&deg[dst[e]], 1.0f);
}

// ---------------------------------------------------------------------------
// Counting sort of the 8E (edge,s) pairs by kernel slot k = widx[p].
// 32 sub-counters per k to kill same-address atomic serialization.
// hist and scatter MUST use identical p->(threadIdx.x&31) mapping.
// ---------------------------------------------------------------------------
__global__ void hist_kernel(const int* __restrict__ widx, int* __restrict__ hist, int P) {
    int p = blockIdx.x * blockDim.x + threadIdx.x;
    if (p >= P) return;
    atomicAdd(&hist[widx[p] * 32 + (threadIdx.x & 31)], 1);
}

// single-block exclusive scan over NHIST=4000 entries; writes off and cur.
__global__ void scan_kernel(const int* __restrict__ hist, int* __restrict__ off,
                            int* __restrict__ cur, int n) {
    __shared__ int l[1024];
    int t = threadIdx.x;
    int v[4];
    int s = 0;
#pragma unroll
    for (int j = 0; j < 4; ++j) {
        int idx = t * 4 + j;
        v[j] = (idx < n) ? hist[idx] : 0;
        s += v[j];
    }
    l[t] = s;
    __syncthreads();
    for (int d = 1; d < 1024; d <<= 1) {
        int tmp = (t >= d) ? l[t - d] : 0;
        __syncthreads();
        l[t] += tmp;
        __syncthreads();
    }
    int base = (t == 0) ? 0 : l[t - 1];
#pragma unroll
    for (int j = 0; j < 4; ++j) {
        int idx = t * 4 + j;
        if (idx < n) {
            off[idx] = base;
            cur[idx] = base;
            base += v[j];
        }
    }
}

__global__ void scatter_kernel(const int* __restrict__ widx, int* __restrict__ cur,
                               int* __restrict__ sorted, int* __restrict__ posOf, int P) {
    int p = blockIdx.x * blockDim.x + threadIdx.x;
    if (p >= P) return;
    int pos = atomicAdd(&cur[widx[p] * 32 + (threadIdx.x & 31)], 1);
    sorted[pos] = p;
    posOf[p] = pos;
}

// ---------------------------------------------------------------------------
// Phase A: pairs in k-sorted order (W[k] stays L1-hot), y at natural index
// layout via (sortedIdx - base). Sub-group of G=OUT_C/4 lanes per pair, each
// lane owns a float4 of output channels. y[(idx-base)][o4] = b * x[src] @ W[k]
// ---------------------------------------------------------------------------
template <int IN_C, int OUT_C>
__global__ __launch_bounds__(256) void phaseA(
    const float* __restrict__ x, const int* __restrict__ src,
    const float* __restrict__ basis, const int* __restrict__ widx,
    const int* __restrict__ sorted, const float* __restrict__ W,
    float* __restrict__ y, int base, int end) {
    constexpr int G = OUT_C / 4;
    const int lane = threadIdx.x & 63;
    const int wv = (blockIdx.x * blockDim.x + threadIdx.x) >> 6;
    const int g = lane / G, og = lane % G;
    constexpr int S = 64 / G;
    int idx = base + wv * S + g;
    if (idx >= end) return;
    int p = sorted[idx];
    int e = p >> 3;
    float b = basis[p];
    int k = widx[p];
    int sn = src[e];
    const float4* __restrict__ Wk = (const float4*)(W + (size_t)k * IN_C * OUT_C);
    const float4* __restrict__ xr = (const float4*)(x + (size_t)sn * IN_C);
    float4 acc = make_float4(0.f, 0.f, 0.f, 0.f);
#pragma unroll
    for (int c = 0; c < IN_C / 4; ++c) {
        float4 xs = xr[c];
        acc = f4fma(xs.x, Wk[(4 * c + 0) * G + og], acc);
        acc = f4fma(xs.y, Wk[(4 * c + 1) * G + og], acc);
        acc = f4fma(xs.z, Wk[(4 * c + 2) * G + og], acc);
        acc = f4fma(xs.w, Wk[(4 * c + 3) * G + og], acc);
    }
    float4 r;
    r.x = b * acc.x; r.y = b * acc.y; r.z = b * acc.z; r.w = b * acc.w;
    ((float4*)y)[(size_t)(idx - base) * G + og] = r;
}

// ---------------------------------------------------------------------------
// Phase B: per edge, sum its 8 pair rows (contiguous-ish gathers via posOf),
// one atomicAdd per output dword per edge (same count as R1 — measured cheap).
// ---------------------------------------------------------------------------
template <int OUT_C>
__global__ __launch_bounds__(256) void phaseB(
    const int* __restrict__ dst, const int* __restrict__ posOf,
    const float* __restrict__ y, float* __restrict__ out,
    int base, int end, int E) {
    constexpr int G = OUT_C / 4;
    const int lane = threadIdx.x & 63;
    const int wv = (blockIdx.x * blockDim.x + threadIdx.x) >> 6;
    const int g = lane / G, og = lane % G;
    constexpr int S = 64 / G;
    int e = wv * S + g;
    if (e >= E) return;
    float4 acc = make_float4(0.f, 0.f, 0.f, 0.f);
    bool any = false;
#pragma unroll
    for (int s = 0; s < 8; ++s) {
        int q = posOf[e * 8 + s];
        if (q >= base && q < end) {
            float4 v = ((const float4*)y)[(size_t)(q - base) * G + og];
            acc.x += v.x; acc.y += v.y; acc.z += v.z; acc.w += v.w;
            any = true;
        }
    }
    if (any) {
        float* o = out + (size_t)dst[e] * OUT_C + 4 * og;
        atomicAdd(o + 0, acc.x);
        atomicAdd(o + 1, acc.y);
        atomicAdd(o + 2, acc.z);
        atomicAdd(o + 3, acc.w);
    }
}

// ---------------------------------------------------------------------------
// Legacy edge-centric conv (kept for conv1 in_c=1 and ws-too-small fallback)
// ---------------------------------------------------------------------------
template <int IN_C, int OUT_C>
__global__ __launch_bounds__(256) void conv_edges(
    const float* __restrict__ x, const int* __restrict__ src,
    const int* __restrict__ dst, const float* __restrict__ basis,
    const int* __restrict__ widx, const float* __restrict__ W,
    float* __restrict__ out, int E) {
    const int lane = threadIdx.x & 63;
    const int wid = threadIdx.x >> 6;
    constexpr int EPW = 64 / OUT_C;
    const int sub = (EPW == 2) ? (lane >> 5) : 0;
    const int o = lane & (OUT_C - 1);
    long e = (long)(blockIdx.x * (blockDim.x >> 6) + wid) * EPW + sub;
    if (e >= E) return;
    const int s_ = src[e];
    const int d_ = dst[e];
    float xv = (o < IN_C) ? x[s_ * IN_C + o] : 0.f;
    float acc = 0.f;
#pragma unroll
    for (int s = 0; s < 8; ++s) {
        const float b = basis[e * 8 + s];
        const int k = widx[e * 8 + s];
        const float* Wk = W + (long)k * IN_C * OUT_C;
#pragma unroll 4
        for (int i = 0; i < IN_C; ++i) {
            float xi = __shfl(xv, i, OUT_C);
            acc = fmaf(b * xi, Wk[i * OUT_C + o], acc);
        }
    }
    atomicAdd(&out[(long)d_ * OUT_C + o], acc);
}

// ---------------------------------------------------------------------------
// Finalize: out = scatter/max(deg,1) + x@R + B, then ELU. In-place.
// ---------------------------------------------------------------------------
template <int IN_C, int OUT_C>
__global__ __launch_bounds__(256) void finalize_k(
    const float* __restrict__ xin, const float* __restrict__ R,
    const float* __restrict__ B, const float* __restrict__ deg,
    float* __restrict__ out, int n) {
    const int lane = threadIdx.x & 63;
    const int wid = threadIdx.x >> 6;
    constexpr int EPW = 64 / OUT_C;
    const int sub = (EPW == 2) ? (lane >> 5) : 0;
    const int o = lane & (OUT_C - 1);
    int j = (blockIdx.x * (blockDim.x >> 6) + wid) * EPW + sub;
    if (j >= n) return;
    float xv = (o < IN_C) ? xin[j * IN_C + o] : 0.f;
    float acc = B[o];
#pragma unroll 4
    for (int i = 0; i < IN_C; ++i) {
        float xi = __shfl(xv, i, OUT_C);
        acc = fmaf(xi, R[i * OUT_C + o], acc);
    }
    float d = fmaxf(deg[j], 1.f);
    float v = out[j * OUT_C + o] / d + acc;
    out[j * OUT_C + o] = (v > 0.f) ? v : expm1f(v);
}

// ---------------------------------------------------------------------------
// Segment max pooling (monotone uint atomicMax; every slot provably written)
// ---------------------------------------------------------------------------
__global__ void pool_scatter(const float* __restrict__ h, const int* __restrict__ cluster,
                             unsigned* __restrict__ pool, int n, int logC) {
    int idx = blockIdx.x * blockDim.x + threadIdx.x;
    if (idx >= (n << logC)) return;
    int j = idx >> logC;
    int c = idx & ((1 << logC) - 1);
    float f = h[idx];
    int b = __float_as_int(f);
    unsigned enc = (b >= 0) ? ((unsigned)b | 0x80000000u) : ~((unsigned)b);
    atomicMax(&pool[(cluster[j] << logC) + c], enc);
}

__global__ void pool_decode(const unsigned* __restrict__ pool, float* __restrict__ out, int total) {
    int idx = blockIdx.x * blockDim.x + threadIdx.x;
    if (idx >= total) return;
    unsigned u = pool[idx];
    int b = (u & 0x80000000u) ? (int)(u & 0x7FFFFFFFu) : (int)(~u);
    out[idx] = __int_as_float(b);
}

// ---------------------------------------------------------------------------
// Head: mean(64x64) -> fc1 -> fc2 -> log_softmax
// ---------------------------------------------------------------------------
__global__ void head_kernel(const float* __restrict__ h, const float* __restrict__ fc1w,
                            const float* __restrict__ fc1b, const float* __restrict__ fc2w,
                            const float* __restrict__ fc2b, float* __restrict__ out) {
    __shared__ float m[64], t[64], u[10];
    int lane = threadIdx.x;
    float s = 0.f;
    for (int j = 0; j < 64; ++j) s += h[j * 64 + lane];
    m[lane] = s * (1.f / 64.f);
    __syncthreads();
    float a = fc1b[lane];
    for (int i = 0; i < 64; ++i) a = fmaf(m[i], fc1w[i * 64 + lane], a);
    t[lane] = a;
    __syncthreads();
    if (lane < 10) {
        float b = fc2b[lane];
        for (int i = 0; i < 64; ++i) b = fmaf(t[i], fc2w[i * 10 + lane], b);
        u[lane] = b;
    }
    __syncthreads();
    if (lane < 10) {
        float mx = u[0];
        for (int i = 1; i < 10; ++i) mx = fmaxf(mx, u[i]);
        float se = 0.f;
        for (int i = 0; i < 10; ++i) se += expf(u[i] - mx);
        out[lane] = u[lane] - mx - logf(se);
    }
}

// ---------------------------------------------------------------------------
// Host-side helpers
// ---------------------------------------------------------------------------
static inline int cdiv(int a, int b) { return (a + b - 1) / b; }

struct Ctx {
    float* basis; int* widx; float* deg;
    int* sorted; int* posOf; int* hist; int* off; int* cur;
    float* y; size_t yElemsAvail;
    bool haveSort;
};

template <int IN_C, int OUT_C>
static void run_conv(const float* xin, float* xout, const float* W, const float* R,
                     const float* B, const int* src, const int* dst, int E, int n,
                     const Ctx& c, hipStream_t stream) {
    const int TB = 256;
    hipMemsetAsync(xout, 0, (size_t)n * OUT_C * 4, stream);
    int P = E * 8;
    size_t PcMax = c.yElemsAvail / OUT_C;
    bool twophase = c.haveSort && PcMax >= 1024;
    if (twophase) {
        constexpr int S = 64 * 4 / OUT_C;  // pairs (or edges) per wave
        int nchunk = (int)((P + PcMax - 1) / PcMax);
        int Pc = cdiv(P, nchunk);
        for (int ch = 0; ch < nchunk; ++ch) {
            int base = ch * Pc;
            int end = (base + Pc < P) ? base + Pc : P;
            int span = end - base;
            phaseA<IN_C, OUT_C><<<cdiv(cdiv(span, S), 4), TB, 0, stream>>>(
                xin, src, c.basis, c.widx, c.sorted, W, c.y, base, end);
            phaseB<OUT_C><<<cdiv(cdiv(E, S), 4), TB, 0, stream>>>(
                dst, c.posOf, c.y, xout, base, end, E);
        }
    } else {
        constexpr int EPW = 64 / OUT_C;
        conv_edges<IN_C, OUT_C><<<cdiv(E, 4 * EPW), TB, 0, stream>>>(
            xin, src, dst, c.basis, c.widx, W, xout, E);
    }
    constexpr int EPW = 64 / OUT_C;
    finalize_k<IN_C, OUT_C><<<cdiv(n, 4 * EPW), TB, 0, stream>>>(xin, R, B, c.deg, xout, n);
}

extern "C" void kernel_launch(void* const* d_in, const int* in_sizes, int n_in,
                              void* d_out, int out_size, void* d_ws, size_t ws_size,
                              hipStream_t stream) {
    const float* x = (const float*)d_in[0];
    const int* src[4] = {(const int*)d_in[1], (const int*)d_in[5], (const int*)d_in[9], (const int*)d_in[13]};
    const int* dst[4] = {(const int*)d_in[2], (const int*)d_in[6], (const int*)d_in[10], (const int*)d_in[14]};
    const float* pseudo[4] = {(const float*)d_in[3], (const float*)d_in[7], (const float*)d_in[11], (const float*)d_in[15]};
    const int* cluster[4] = {(const int*)d_in[4], (const int*)d_in[8], (const int*)d_in[12], (const int*)d_in[16]};
    const float* Wp[8], *Rp[8], *Bp[8];
    for (int l = 0; l < 8; ++l) {
        Wp[l] = (const float*)d_in[17 + 3 * l];
        Rp[l] = (const float*)d_in[18 + 3 * l];
        Bp[l] = (const float*)d_in[19 + 3 * l];
    }
    const float* fc1w = (const float*)d_in[41];
    const float* fc1b = (const float*)d_in[42];
    const float* fc2w = (const float*)d_in[43];
    const float* fc2b = (const float*)d_in[44];
    float* outp = (float*)d_out;

    const int NS[5] = {16384, 4096, 1024, 256, 64};
    const int ES[4] = {16384 * 8, 4096 * 8, 1024 * 8, 256 * 8};
    const int PMAX = ES[0] * 8;  // 1,048,576

    // ---- workspace layout (each section 256B-aligned) ----
    char* w = (char*)d_ws;
    auto take = [&](size_t bytes) -> char* {
        char* r = w;
        w += (bytes + 255) & ~(size_t)255;
        return r;
    };
    Ctx c;
    c.basis = (float*)take((size_t)PMAX * 4);
    c.widx = (int*)take((size_t)PMAX * 4);
    c.deg = (float*)take((size_t)NS[0] * 4);
    float* bufA = (float*)take((size_t)NS[0] * 64 * 4);
    float* bufB = (float*)take((size_t)NS[0] * 64 * 4);
    unsigned* pool = (unsigned*)take((size_t)NS[1] * 64 * 4);
    c.sorted = (int*)take((size_t)PMAX * 4);
    c.posOf = (int*)take((size_t)PMAX * 4);
    c.hist = (int*)take((size_t)NHIST * 4);
    c.off = (int*)take((size_t)NHIST * 4);
    c.cur = (int*)take((size_t)NHIST * 4);
    size_t fixedBytes = (size_t)(w - (char*)d_ws);
    c.haveSort = ws_size > fixedBytes + (1 << 20);
    c.y = (float*)w;
    c.yElemsAvail = c.haveSort ? (ws_size - fixedBytes) / 4 : 0;

    const int TB = 256;

    auto level_pre = [&](int l) {
        int E = ES[l], P = E * 8, n = NS[l];
        basis_kernel<<<cdiv(E, TB), TB, 0, stream>>>(pseudo[l], c.basis, c.widx, E);
        hipMemsetAsync(c.deg, 0, n * 4, stream);
        deg_kernel<<<cdiv(E, TB), TB, 0, stream>>>(dst[l], c.deg, E);
        if (c.haveSort) {
            hipMemsetAsync(c.hist, 0, NHIST * 4, stream);
            hist_kernel<<<cdiv(P, TB), TB, 0, stream>>>(c.widx, c.hist, P);
            scan_kernel<<<1, 1024, 0, stream>>>(c.hist, c.off, c.cur, NHIST);
            scatter_kernel<<<cdiv(P, TB), TB, 0, stream>>>(c.widx, c.cur, c.sorted, c.posOf, P);
        }
    };

    // ===== Level 0: n=16384, conv1 (1->32, legacy: W traffic tiny), conv12 (32->32)
    {
        int E = ES[0], n = NS[0];
        level_pre(0);
        // conv1 legacy (in_c=1 -> per-edge W row is only 32 floats)
        hipMemsetAsync(bufA, 0, (size_t)n * 32 * 4, stream);
        conv_edges<1, 32><<<cdiv(E, 8), TB, 0, stream>>>(x, src[0], dst[0], c.basis, c.widx, Wp[0], bufA, E);
        finalize_k<1, 32><<<cdiv(n, 8), TB, 0, stream>>>(x, Rp[0], Bp[0], c.deg, bufA, n);
        // conv12 two-phase
        run_conv<32, 32>(bufA, bufB, Wp[1], Rp[1], Bp[1], src[0], dst[0], E, n, c, stream);
        // pool -> bufA (4096 x 32)
        hipMemsetAsync(pool, 0, (size_t)NS[1] * 32 * 4, stream);
        pool_scatter<<<cdiv(n * 32, TB), TB, 0, stream>>>(bufB, cluster[0], pool, n, 5);
        pool_decode<<<cdiv(NS[1] * 32, TB), TB, 0, stream>>>(pool, bufA, NS[1] * 32);
    }
    // ===== Level 1: n=4096, conv2 (32->64), conv3 (64->64)
    {
        int E = ES[1], n = NS[1];
        level_pre(1);
        run_conv<32, 64>(bufA, bufB, Wp[2], Rp[2], Bp[2], src[1], dst[1], E, n, c, stream);
        run_conv<64, 64>(bufB, bufA, Wp[3], Rp[3], Bp[3], src[1], dst[1], E, n, c, stream);
        hipMemsetAsync(pool, 0, (size_t)NS[2] * 64 * 4, stream);
        pool_scatter<<<cdiv(n * 64, TB), TB, 0, stream>>>(bufA, cluster[1], pool, n, 6);
        pool_decode<<<cdiv(NS[2] * 64, TB), TB, 0, stream>>>(pool, bufB, NS[2] * 64);
    }
    // ===== Level 2: n=1024, conv4, conv5 (64->64)
    {
        int E = ES[2], n = NS[2];
        level_pre(2);
        run_conv<64, 64>(bufB, bufA, Wp[4], Rp[4], Bp[4], src[2], dst[2], E, n, c, stream);
        run_conv<64, 64>(bufA, bufB, Wp[5], Rp[5], Bp[5], src[2], dst[2], E, n, c, stream);
        hipMemsetAsync(pool, 0, (size_t)NS[3] * 64 * 4, stream);
        pool_scatter<<<cdiv(n * 64, TB), TB, 0, stream>>>(bufB, cluster[2], pool, n, 6);
        pool_decode<<<cdiv(NS[3] * 64, TB), TB, 0, stream>>>(pool, bufA, NS[3] * 64);
    }
    // ===== Level 3: n=256, conv6, conv7 (64->64)
    {
        int E = ES[3], n = NS[3];
        level_pre(3);
        run_conv<64, 64>(bufA, bufB, Wp[6], Rp[6], Bp[6], src[3], dst[3], E, n, c, stream);
        run_conv<64, 64>(bufB, bufA, Wp[7], Rp[7], Bp[7], src[3], dst[3], E, n, c, stream);
        hipMemsetAsync(pool, 0, (size_t)NS[4] * 64 * 4, stream);
        pool_scatter<<<cdiv(n * 64, TB), TB, 0, stream>>>(bufA, cluster[3], pool, n, 6);
        pool_decode<<<cdiv(NS[4] * 64, TB), TB, 0, stream>>>(pool, bufB, NS[4] * 64);
    }
    // ===== Head
    head_kernel<<<1, 64, 0, stream>>>(bufB, fc1w, fc1b, fc2w, fc2b, outp);
}